// Round 1
// baseline (45.236 us; speedup 1.0000x reference)
//
#include <hip/hip_runtime.h>
#include <stdint.h>

#define NB    4
#define NL0   2048
#define NL1   2048
#define NC    64
#define KMAX  128
#define CAP   256
#define NG1   9
#define NBINS 729
#define FLOWN (NB*NL0*3)

__global__ __launch_bounds__(256) void fine_match_kernel(
    const float* __restrict__ x0, const float* __restrict__ x1,
    const float* __restrict__ pos0, const float* __restrict__ pos1,
    const void* __restrict__ padraw, float* __restrict__ out)
{
  __shared__ float   s_pos1[NL1*3];
  __shared__ uint8_t s_pad[NL1];
  __shared__ float   s_x0[4][NC];
  __shared__ float   s_p0[4][3];
  __shared__ float   s_d2[4][CAP];
  __shared__ int     s_jj[4][CAP];
  __shared__ float   s_bins[4][NBINS];
  __shared__ int     s_a01, s_af;

  const int t = threadIdx.x;
  const int bid = blockIdx.x;
  const int b = bid >> 9;               // 512 blocks per batch
  const int l0base = (bid & 511) << 2;  // 4 queries per block

  if (t == 0) { s_a01 = 1; s_af = 1; }
  __syncthreads();

  // ---- pad_mask dtype detection on first NB*NL1 bytes (safe for u8/i32/f32) ----
  {
    const uint32_t* pi = (const uint32_t*)padraw;
    bool a01 = true, af = true;
    for (int i = t; i < (NB*NL1)/4; i += 256) {
      const uint32_t v = pi[i];
      a01 = a01 && (v == 0u || v == 1u);
      af  = af  && (v == 0u || v == 0x3F800000u);
    }
    if (!a01) atomicAnd(&s_a01, 0);
    if (!af)  atomicAnd(&s_af, 0);
  }

  // ---- stage pos1[b], x0 rows, pos0 rows; zero bins ----
  const float* p1b = pos1 + b*NL1*3;
  for (int i = t; i < NL1*3; i += 256) s_pos1[i] = p1b[i];
  {
    const int q = t >> 6, c = t & 63;
    s_x0[q][c] = x0[(b*NL0 + l0base + q)*NC + c];
  }
  if (t < 12) {
    const int q = t / 3, c = t - q*3;
    s_p0[q][c] = pos0[(b*NL0 + l0base + q)*3 + c];
  }
  for (int i = t; i < 4*NBINS; i += 256) (&s_bins[0][0])[i] = 0.0f;
  __syncthreads();

  {
    const int mode = s_a01 ? 1 : (s_af ? 2 : 0);
    if (mode == 1) {
      const int32_t* p = (const int32_t*)padraw + b*NL1;
      for (int i = t; i < NL1; i += 256) s_pad[i] = (p[i] != 0);
    } else if (mode == 2) {
      const float* p = (const float*)padraw + b*NL1;
      for (int i = t; i < NL1; i += 256) s_pad[i] = (p[i] != 0.0f);
    } else {
      const uint8_t* p = (const uint8_t*)padraw + b*NL1;
      for (int i = t; i < NL1; i += 256) s_pad[i] = p[i];
    }
  }
  __syncthreads();

  const int wv = t >> 6, lane = t & 63;
  const int l0 = l0base + wv;
  const float p0x = s_p0[wv][0], p0y = s_p0[wv][1], p0z = s_p0[wv][2];

  // ---- phase 1: radius scan + wave compaction (list ordered by j) ----
  int cnt = 0;
  for (int base = 0; base < NL1; base += 64) {
    const int j = base + lane;
    const float dx = __fsub_rn(s_pos1[j*3+0], p0x);
    const float dy = __fsub_rn(s_pos1[j*3+1], p0y);
    const float dz = __fsub_rn(s_pos1[j*3+2], p0z);
    const float d2 = __fadd_rn(__fadd_rn(__fmul_rn(dx,dx), __fmul_rn(dy,dy)), __fmul_rn(dz,dz));
    const bool ok = d2 < 0.0324f;                 // strict <, matches reference
    const uint64_t m = __ballot(ok);
    if (ok) {
      const int pos = cnt + (int)__popcll(m & ((1ull << lane) - 1ull));
      if (pos < CAP) { s_d2[wv][pos] = d2; s_jj[wv][pos] = j; }
    }
    cnt += (int)__popcll(m);
  }
  if (cnt > CAP) cnt = CAP;
  __syncthreads();   // LDS visibility for compacted lists

  // ---- phase 2: pad filter, rare exact top-K select, correlation ----
  const bool over = (cnt > KMAX);
  float corr[4]; int jj[4]; bool keep[4];
  for (int s = 0; s < 4; ++s) {
    keep[s] = false; corr[s] = -1e30f; jj[s] = 0;
    const int i = lane + 64*s;
    if (i < cnt) {
      const int j = s_jj[wv][i];
      jj[s] = j;
      bool k = (s_pad[j] == 0);
      if (over && k) {   // rank over ALL in-radius candidates (incl. padded), tie-break by index
        const float di = s_d2[wv][i];
        int rank = 0;
        for (int m2 = 0; m2 < cnt; ++m2) {
          const float dm = s_d2[wv][m2];
          rank += (dm < di || (dm == di && m2 < i)) ? 1 : 0;
        }
        if (rank >= KMAX) k = false;
      }
      if (k) {
        const float* xr = x1 + (b*NL1 + j)*NC;
        float acc = 0.0f;
        #pragma unroll
        for (int c = 0; c < NC; c += 4) {
          const float4 v = *(const float4*)(xr + c);
          acc += s_x0[wv][c+0]*v.x + s_x0[wv][c+1]*v.y
               + s_x0[wv][c+2]*v.z + s_x0[wv][c+3]*v.w;
        }
        corr[s] = acc * 0.125f;   // / sqrt(64), exact
        keep[s] = true;
      }
    }
  }

  // ---- phase 3: wave softmax over <=128 kept candidates ----
  float mx = -1e30f;
  for (int s = 0; s < 4; ++s) if (keep[s] && corr[s] > mx) mx = corr[s];
  for (int off = 32; off; off >>= 1) { const float o = __shfl_xor(mx, off); if (o > mx) mx = o; }
  float pr[4]; float sum = 0.0f;
  for (int s = 0; s < 4; ++s) { pr[s] = keep[s] ? expf(corr[s] - mx) : 0.0f; sum += pr[s]; }
  for (int off = 32; off; off >>= 1) sum += __shfl_xor(sum, off);
  const float inv = (sum > 0.0f) ? (1.0f / sum) : 0.0f;

  // ---- phase 4: flow + voxel scatter (LDS atomics) ----
  float fx = 0.0f, fy = 0.0f, fz = 0.0f;
  for (int s = 0; s < 4; ++s) {
    if (!keep[s]) continue;
    const float pv = pr[s] * inv;
    const int j = jj[s];
    const float dx = __fsub_rn(s_pos1[j*3+0], p0x);
    const float dy = __fsub_rn(s_pos1[j*3+1], p0y);
    const float dz = __fsub_rn(s_pos1[j*3+2], p0z);
    fx += pv*dx; fy += pv*dy; fz += pv*dz;
    const float cx = __fdiv_rn(__fadd_rn(dx, 0.16f), 0.04f);
    const float cy = __fdiv_rn(__fadd_rn(dy, 0.16f), 0.04f);
    const float cz = __fdiv_rn(__fadd_rn(dz, 0.16f), 0.04f);
    int vx = (int)rintf(cx); vx = vx < 0 ? 0 : (vx > 8 ? 8 : vx);
    int vy = (int)rintf(cy); vy = vy < 0 ? 0 : (vy > 8 ? 8 : vy);
    int vz = (int)rintf(cz); vz = vz < 0 ? 0 : (vz > 8 ? 8 : vz);
    atomicAdd(&s_bins[wv][(vx*NG1 + vy)*NG1 + vz], pv);
  }
  for (int off = 32; off; off >>= 1) {
    fx += __shfl_xor(fx, off); fy += __shfl_xor(fy, off); fz += __shfl_xor(fz, off);
  }
  if (lane == 0) {
    float* f = out + (b*NL0 + l0)*3;
    f[0] = fx; f[1] = fy; f[2] = fz;
  }
  __syncthreads();

  // ---- phase 5: coalesced writeout of 4x729 contiguous bins (includes zeros) ----
  float* fd = out + FLOWN + (size_t)(b*NL0 + l0base)*NBINS;
  for (int i = t; i < 4*NBINS; i += 256) fd[i] = (&s_bins[0][0])[i];
}

extern "C" void kernel_launch(void* const* d_in, const int* in_sizes, int n_in,
                              void* d_out, int out_size, void* d_ws, size_t ws_size,
                              hipStream_t stream) {
  const float* x0   = (const float*)d_in[0];
  const float* x1   = (const float*)d_in[1];
  const float* pos0 = (const float*)d_in[2];
  const float* pos1 = (const float*)d_in[3];
  const void*  pad  = d_in[4];
  float* out = (float*)d_out;
  (void)in_sizes; (void)n_in; (void)out_size; (void)d_ws; (void)ws_size;
  hipLaunchKernelGGL(fine_match_kernel, dim3(NB*NL0/4), dim3(256), 0, stream,
                     x0, x1, pos0, pos1, pad, out);
}

// Round 2
// 32.362 us; speedup vs baseline: 1.3978x; 1.3978x over previous
//
#include <hip/hip_runtime.h>
#include <stdint.h>

#define NB    4
#define NL0   2048
#define NL1   2048
#define NC    64
#define KMAX  128
#define CAP   256
#define NG1   9
#define NBINS 729
#define FLOWN (NB*NL0*3)
#define QPB   8      // queries per block, 1 per wave
#define TPB   512

__global__ __launch_bounds__(TPB, 6) void fine_match_kernel(
    const float* __restrict__ x0, const float* __restrict__ x1,
    const float* __restrict__ pos0, const float* __restrict__ pos1,
    const void* __restrict__ padraw, float* __restrict__ out)
{
  __shared__ float          s_pos[3][NL1];     // SoA: x | y | z
  __shared__ uint8_t        s_pad[NL1];
  __shared__ float          s_x0[QPB][NC];
  __shared__ float          s_p0[QPB][3];
  __shared__ unsigned short s_jj[QPB][CAP];
  __shared__ float          s_flow[QPB][3];
  __shared__ int            s_a01, s_af;

  const int t = threadIdx.x;
  const int bid = blockIdx.x;
  const int b = bid >> 8;                 // 256 blocks per batch
  const int l0base = (bid & 255) * QPB;

  if (t == 0) { s_a01 = 1; s_af = 1; }
  __syncthreads();  // B1

  // ---- pad_mask dtype detection (u8 / i32 / f32 all safe to scan as u32) ----
  {
    const uint32_t* pi = (const uint32_t*)padraw;
    bool a01 = true, af = true;
    for (int i = t; i < (NB*NL1)/4; i += TPB) {
      const uint32_t v = pi[i];
      a01 = a01 && (v == 0u || v == 1u);
      af  = af  && (v == 0u || v == 0x3F800000u);
    }
    if (!a01) atomicAnd(&s_a01, 0);
    if (!af)  atomicAnd(&s_af, 0);
  }

  // ---- stage pos1 (AoS->SoA), x0 rows, pos0 rows; zero global bins ----
  {
    const float* p1b = pos1 + b*NL1*3;
    for (int i = t; i < NL1*3; i += TPB) {
      const float v = p1b[i];
      const int j = i / 3, c = i - j*3;
      s_pos[c][j] = v;
    }
  }
  { // TPB == QPB*NC exactly
    const int q = t >> 6, c = t & 63;
    s_x0[q][c] = x0[(b*NL0 + l0base + q)*NC + c];
  }
  if (t < QPB*3) {
    const int q = t / 3, c = t - q*3;
    s_p0[q][c] = pos0[(b*NL0 + l0base + q)*3 + c];
  }
  { // zero this block's 8x729 flow_dist region (16B-aligned: l0base%8==0)
    float4 z4; z4.x = z4.y = z4.z = z4.w = 0.0f;
    float4* bz = (float4*)(out + FLOWN + (size_t)(b*NL0 + l0base)*NBINS);
    for (int i = t; i < QPB*NBINS/4; i += TPB) bz[i] = z4;
  }
  __syncthreads();  // B2 (drains zero-stores to L2 before any atomics)

  // ---- decode pad per detected dtype ----
  {
    const int mode = s_a01 ? 1 : (s_af ? 2 : 0);
    if (mode == 1) {
      const int32_t* p = (const int32_t*)padraw + b*NL1;
      for (int i = t; i < NL1; i += TPB) s_pad[i] = (p[i] != 0);
    } else if (mode == 2) {
      const float* p = (const float*)padraw + b*NL1;
      for (int i = t; i < NL1; i += TPB) s_pad[i] = (p[i] != 0.0f);
    } else {
      const uint8_t* p = (const uint8_t*)padraw + b*NL1;
      for (int i = t; i < NL1; i += TPB) s_pad[i] = p[i];
    }
  }
  __syncthreads();  // B3

  const int wv = t >> 6, lane = t & 63;
  const int l0 = l0base + wv;
  const float p0x = s_p0[wv][0], p0y = s_p0[wv][1], p0z = s_p0[wv][2];

  // ---- phase 1: radius scan + wave compaction (ordered by j) ----
  int cnt = 0;
  for (int base = 0; base < NL1; base += 64) {
    const int j = base + lane;
    const float dx = __fsub_rn(s_pos[0][j], p0x);
    const float dy = __fsub_rn(s_pos[1][j], p0y);
    const float dz = __fsub_rn(s_pos[2][j], p0z);
    const float d2 = __fadd_rn(__fadd_rn(__fmul_rn(dx,dx), __fmul_rn(dy,dy)), __fmul_rn(dz,dz));
    const bool ok = d2 < 0.0324f;              // strict <, matches reference
    const uint64_t m = __ballot(ok);
    if (ok) {
      const int pos = cnt + (int)__popcll(m & ((1ull << lane) - 1ull));
      if (pos < CAP) s_jj[wv][pos] = (unsigned short)j;
    }
    cnt += (int)__popcll(m);
  }
  if (cnt > CAP) cnt = CAP;
  __syncthreads();  // B4

  // ---- phase 2: pad filter, rare exact rank-select, correlation ----
  const bool over = (cnt > KMAX);
  float corr[4]; bool keep[4];
  #pragma unroll
  for (int s = 0; s < 4; ++s) {
    keep[s] = false; corr[s] = -1e30f;
    const int i = lane + 64*s;
    if (i < cnt) {
      const int j = (int)s_jj[wv][i];
      bool k = (s_pad[j] == 0);
      if (over && k) {  // rank over ALL in-radius candidates, tie-break by list order
        const float dx = __fsub_rn(s_pos[0][j], p0x);
        const float dy = __fsub_rn(s_pos[1][j], p0y);
        const float dz = __fsub_rn(s_pos[2][j], p0z);
        const float di = __fadd_rn(__fadd_rn(__fmul_rn(dx,dx), __fmul_rn(dy,dy)), __fmul_rn(dz,dz));
        int rank = 0;
        for (int m2 = 0; m2 < cnt; ++m2) {
          const int jm = (int)s_jj[wv][m2];
          const float ex = __fsub_rn(s_pos[0][jm], p0x);
          const float ey = __fsub_rn(s_pos[1][jm], p0y);
          const float ez = __fsub_rn(s_pos[2][jm], p0z);
          const float dm = __fadd_rn(__fadd_rn(__fmul_rn(ex,ex), __fmul_rn(ey,ey)), __fmul_rn(ez,ez));
          rank += (dm < di || (dm == di && m2 < i)) ? 1 : 0;
        }
        if (rank >= KMAX) k = false;
      }
      if (k) {
        const float* xr = x1 + (b*NL1 + j)*NC;
        float acc = 0.0f;
        #pragma unroll
        for (int c = 0; c < NC; c += 4) {
          const float4 v = *(const float4*)(xr + c);
          acc += s_x0[wv][c+0]*v.x + s_x0[wv][c+1]*v.y
               + s_x0[wv][c+2]*v.z + s_x0[wv][c+3]*v.w;
        }
        corr[s] = acc * 0.125f;   // / sqrt(64)
        keep[s] = true;
      }
    }
  }

  // ---- phase 3: wave softmax over <=128 kept candidates ----
  float mx = -1e30f;
  #pragma unroll
  for (int s = 0; s < 4; ++s) if (keep[s] && corr[s] > mx) mx = corr[s];
  for (int off = 32; off; off >>= 1) { const float o = __shfl_xor(mx, off); if (o > mx) mx = o; }
  float pr[4]; float sum = 0.0f;
  #pragma unroll
  for (int s = 0; s < 4; ++s) { pr[s] = keep[s] ? expf(corr[s] - mx) : 0.0f; sum += pr[s]; }
  for (int off = 32; off; off >>= 1) sum += __shfl_xor(sum, off);
  const float inv = (sum > 0.0f) ? (1.0f / sum) : 0.0f;

  // ---- phase 4: flow + voxel scatter (workgroup-scope atomics into local L2) ----
  float* bins = out + FLOWN + (size_t)(b*NL0 + l0)*NBINS;
  float fx = 0.0f, fy = 0.0f, fz = 0.0f;
  #pragma unroll
  for (int s = 0; s < 4; ++s) {
    if (!keep[s]) continue;
    const float pv = pr[s] * inv;
    const int j = (int)s_jj[wv][lane + 64*s];
    const float dx = __fsub_rn(s_pos[0][j], p0x);
    const float dy = __fsub_rn(s_pos[1][j], p0y);
    const float dz = __fsub_rn(s_pos[2][j], p0z);
    fx += pv*dx; fy += pv*dy; fz += pv*dz;
    const float cx = __fdiv_rn(__fadd_rn(dx, 0.16f), 0.04f);
    const float cy = __fdiv_rn(__fadd_rn(dy, 0.16f), 0.04f);
    const float cz = __fdiv_rn(__fadd_rn(dz, 0.16f), 0.04f);
    int vx = (int)rintf(cx); vx = vx < 0 ? 0 : (vx > 8 ? 8 : vx);
    int vy = (int)rintf(cy); vy = vy < 0 ? 0 : (vy > 8 ? 8 : vy);
    int vz = (int)rintf(cz); vz = vz < 0 ? 0 : (vz > 8 ? 8 : vz);
    __hip_atomic_fetch_add(&bins[(vx*NG1 + vy)*NG1 + vz], pv,
                           __ATOMIC_RELAXED, __HIP_MEMORY_SCOPE_WORKGROUP);
  }
  for (int off = 32; off; off >>= 1) {
    fx += __shfl_xor(fx, off); fy += __shfl_xor(fy, off); fz += __shfl_xor(fz, off);
  }
  if (lane == 0) { s_flow[wv][0] = fx; s_flow[wv][1] = fy; s_flow[wv][2] = fz; }
  __syncthreads();  // B5

  if (t < QPB*3) {
    float* f = out + (size_t)(b*NL0 + l0base)*3;
    f[t] = (&s_flow[0][0])[t];
  }
}

extern "C" void kernel_launch(void* const* d_in, const int* in_sizes, int n_in,
                              void* d_out, int out_size, void* d_ws, size_t ws_size,
                              hipStream_t stream) {
  const float* x0   = (const float*)d_in[0];
  const float* x1   = (const float*)d_in[1];
  const float* pos0 = (const float*)d_in[2];
  const float* pos1 = (const float*)d_in[3];
  const void*  pad  = d_in[4];
  float* out = (float*)d_out;
  (void)in_sizes; (void)n_in; (void)out_size; (void)d_ws; (void)ws_size;
  hipLaunchKernelGGL(fine_match_kernel, dim3(NB*NL0/QPB), dim3(TPB), 0, stream,
                     x0, x1, pos0, pos1, pad, out);
}